// Round 1
// baseline (701.672 us; speedup 1.0000x reference)
//
#include <hip/hip_runtime.h>
#include <math.h>

// Problem constants (B,Cin,H,W)=(8,128,64,64), Cout=256, K=3, stride=1, pad=1, dil=1
#define B_    8
#define CIN   128
#define Hx    64
#define Wx    64
#define COUT  256
#define NKK   9
#define HW    4096      // 64*64
#define KTOT  1152      // CIN*9
#define NOFF  18        // 2*K*K

// ws layout (float offsets):
//   off    [B][18][HW]    @ 0         (589824)
//   Wt     [1152][256]    @ 589824    (294912)   Wt[kk*128+cin][cout] = w[cout][cin][kk]
//   y      [B][256][HW]   @ 884736    (8388608)
//   mean   [256]          @ 9273344
//   invstd [256]          @ 9273600
// total 9273856 floats = 37.1 MB

// ---------------- K1: offset conv (3x3, pad 1) ----------------
// thread = (b, kk, ho, wo); computes both dy (c=2kk) and dx (c=2kk+1).
__global__ __launch_bounds__(256) void offset_conv_kernel(
    const float* __restrict__ x, const float* __restrict__ ow,
    const float* __restrict__ ob, float* __restrict__ off) {
  int t = blockIdx.x * blockDim.x + threadIdx.x;   // 8*9*4096 = 294912
  int wo = t & 63;
  int ho = (t >> 6) & 63;
  int kk = (t >> 12) % 9;
  int b  = t / (9 * HW);
  const float* w0 = ow + (2 * kk) * KTOT;          // [cin][3][3]
  const float* w1 = ow + (2 * kk + 1) * KTOT;
  const float* xb = x + b * CIN * HW;
  float a0 = 0.f, a1 = 0.f;
  for (int cin = 0; cin < CIN; ++cin) {
    const float* xp  = xb + cin * HW;
    const float* wp0 = w0 + cin * 9;
    const float* wp1 = w1 + cin * 9;
#pragma unroll
    for (int ky = 0; ky < 3; ++ky) {
      int iy = ho - 1 + ky;
      bool rok = (iy >= 0) && (iy < Hx);
      const float* row = xp + iy * Wx;
#pragma unroll
      for (int kx = 0; kx < 3; ++kx) {
        int ix = wo - 1 + kx;
        float v = (rok && ix >= 0 && ix < Wx) ? row[ix] : 0.f;
        a0 = fmaf(v, wp0[ky * 3 + kx], a0);
        a1 = fmaf(v, wp1[ky * 3 + kx], a1);
      }
    }
  }
  off[(b * NOFF + 2 * kk) * HW + ho * 64 + wo]     = a0 + ob[2 * kk];
  off[(b * NOFF + 2 * kk + 1) * HW + ho * 64 + wo] = a1 + ob[2 * kk + 1];
}

// ---------------- K2: weight transpose ----------------
// Wt[kk*128+cin][cout] = w[cout][cin][kk]
__global__ __launch_bounds__(256) void wt_transpose_kernel(
    const float* __restrict__ w, float* __restrict__ Wt) {
  int t = blockIdx.x * blockDim.x + threadIdx.x;   // 1152*256 = 294912
  int cout = t & 255;
  int m = t >> 8;                                  // 0..1151
  int kk = m >> 7;                                 // m = kk*128+cin
  int cin = m & 127;
  Wt[m * 256 + cout] = w[(cout * CIN + cin) * 9 + kk];
}

// ---------------- K3: fused bilinear-sample + GEMM ----------------
// C-tile 64(cout) x 64(pos=wo row), K=1152 in chunks of 16.
// block -> (cout_tile 0..3, b 0..7, ho 0..63); 2048 blocks, 256 threads.
__global__ __launch_bounds__(256) void deform_gemm_kernel(
    const float* __restrict__ x, const float* __restrict__ off,
    const float* __restrict__ Wt, const float* __restrict__ db,
    float* __restrict__ y) {
  __shared__ __align__(16) float sm_a[16 * 64];
  __shared__ __align__(16) float sm_b[16 * 64];
  __shared__ int4   sm_idx[NKK * 64];
  __shared__ float4 sm_wt[NKK * 64];

  int bb = blockIdx.x;
  int cout0 = (bb & 3) << 6;
  int pt = bb >> 2;           // 0..511
  int b  = pt >> 6;
  int ho = pt & 63;
  int tid = threadIdx.x;

  // phase 0: bilinear coefficients per (tap, wo)
  for (int i = tid; i < NKK * 64; i += 256) {
    int kk = i >> 6, wo = i & 63;
    float dy = off[(b * NOFF + 2 * kk) * HW + ho * 64 + wo];
    float dx = off[(b * NOFF + 2 * kk + 1) * HW + ho * 64 + wo];
    float sy = (float)(ho - 1 + kk / 3) + dy;
    float sx = (float)(wo - 1 + kk % 3) + dx;
    float fy = floorf(sy), fx = floorf(sx);
    int y0 = (int)fy, x0 = (int)fx;
    float wy = sy - fy, wx = sx - fx;
    int y1 = y0 + 1, x1 = x0 + 1;
    int cy0 = min(max(y0, 0), Hx - 1), cy1 = min(max(y1, 0), Hx - 1);
    int cx0 = min(max(x0, 0), Wx - 1), cx1 = min(max(x1, 0), Wx - 1);
    bool vy0 = (y0 >= 0) && (y0 < Hx), vy1 = (y1 >= 0) && (y1 < Hx);
    bool vx0 = (x0 >= 0) && (x0 < Wx), vx1 = (x1 >= 0) && (x1 < Wx);
    int4 id;
    id.x = cy0 * Wx + cx0; id.y = cy0 * Wx + cx1;
    id.z = cy1 * Wx + cx0; id.w = cy1 * Wx + cx1;
    float4 wv;
    wv.x = (vy0 && vx0) ? (1.f - wy) * (1.f - wx) : 0.f;
    wv.y = (vy0 && vx1) ? (1.f - wy) * wx : 0.f;
    wv.z = (vy1 && vx0) ? wy * (1.f - wx) : 0.f;
    wv.w = (vy1 && vx1) ? wy * wx : 0.f;
    sm_idx[i] = id; sm_wt[i] = wv;
  }
  __syncthreads();

  int ty = tid >> 4, tx = tid & 15;         // compute roles
  int pos = tid & 63, rb = tid >> 6;        // B-staging roles
  int ar = tid >> 4, ac4 = tid & 15;        // A-staging roles
  const float* xb = x + b * CIN * HW;

  float4 acc0 = {0.f, 0.f, 0.f, 0.f};
  float4 acc1 = acc0, acc2 = acc0, acc3 = acc0;

  for (int kc = 0; kc < 72; ++kc) {
    int kk = kc >> 3;
    int cin0 = (kc & 7) << 4;
    // stage A: 16x64 weight tile (Wt row-major [k][cout])
    *(float4*)&sm_a[ar * 64 + ac4 * 4] =
        *(const float4*)&Wt[(kk * 128 + cin0 + ar) * 256 + cout0 + ac4 * 4];
    // stage B: 16x64 sampled-patch tile
    int4 id = sm_idx[kk * 64 + pos];
    float4 wv = sm_wt[kk * 64 + pos];
#pragma unroll
    for (int j = 0; j < 4; ++j) {
      int r = rb * 4 + j;
      const float* xp = xb + (cin0 + r) * HW;
      float v = wv.x * xp[id.x] + wv.y * xp[id.y] + wv.z * xp[id.z] + wv.w * xp[id.w];
      sm_b[r * 64 + pos] = v;
    }
    __syncthreads();
#pragma unroll
    for (int k = 0; k < 16; ++k) {
      float4 av = *(const float4*)&sm_a[k * 64 + ty * 4];
      float4 bv = *(const float4*)&sm_b[k * 64 + tx * 4];
      acc0.x = fmaf(av.x, bv.x, acc0.x); acc0.y = fmaf(av.x, bv.y, acc0.y);
      acc0.z = fmaf(av.x, bv.z, acc0.z); acc0.w = fmaf(av.x, bv.w, acc0.w);
      acc1.x = fmaf(av.y, bv.x, acc1.x); acc1.y = fmaf(av.y, bv.y, acc1.y);
      acc1.z = fmaf(av.y, bv.z, acc1.z); acc1.w = fmaf(av.y, bv.w, acc1.w);
      acc2.x = fmaf(av.z, bv.x, acc2.x); acc2.y = fmaf(av.z, bv.y, acc2.y);
      acc2.z = fmaf(av.z, bv.z, acc2.z); acc2.w = fmaf(av.z, bv.w, acc2.w);
      acc3.x = fmaf(av.w, bv.x, acc3.x); acc3.y = fmaf(av.w, bv.y, acc3.y);
      acc3.z = fmaf(av.w, bv.z, acc3.z); acc3.w = fmaf(av.w, bv.w, acc3.w);
    }
    __syncthreads();
  }

  // epilogue: + dconv bias, store y
  int crow = cout0 + ty * 4;
  float b0 = db[crow], b1 = db[crow + 1], b2 = db[crow + 2], b3 = db[crow + 3];
  acc0.x += b0; acc0.y += b0; acc0.z += b0; acc0.w += b0;
  acc1.x += b1; acc1.y += b1; acc1.z += b1; acc1.w += b1;
  acc2.x += b2; acc2.y += b2; acc2.z += b2; acc2.w += b2;
  acc3.x += b3; acc3.y += b3; acc3.z += b3; acc3.w += b3;
  float* yb = y + (b * COUT + crow) * HW + ho * 64 + tx * 4;
  *(float4*)yb            = acc0;
  *(float4*)(yb + HW)     = acc1;
  *(float4*)(yb + 2 * HW) = acc2;
  *(float4*)(yb + 3 * HW) = acc3;
}

// ---------------- K4: BN batch stats (per channel) ----------------
__global__ __launch_bounds__(256) void bn_stats_kernel(
    const float* __restrict__ y, float* __restrict__ mean, float* __restrict__ invstd) {
  int c = blockIdx.x;
  int tid = threadIdx.x;
  float s = 0.f, s2 = 0.f;
  for (int b = 0; b < B_; ++b) {
    const float* p = y + (b * COUT + c) * HW;
    for (int i = tid; i < HW; i += 256) {
      float v = p[i];
      s += v; s2 = fmaf(v, v, s2);
    }
  }
#pragma unroll
  for (int o = 32; o > 0; o >>= 1) {
    s  += __shfl_down(s, o);
    s2 += __shfl_down(s2, o);
  }
  __shared__ float rs[4], rs2[4];
  int wid = tid >> 6, lane = tid & 63;
  if (lane == 0) { rs[wid] = s; rs2[wid] = s2; }
  __syncthreads();
  if (tid == 0) {
    float S  = rs[0] + rs[1] + rs[2] + rs[3];
    float S2 = rs2[0] + rs2[1] + rs2[2] + rs2[3];
    float m = S / 32768.f;
    float var = S2 / 32768.f - m * m;
    mean[c] = m;
    invstd[c] = rsqrtf(var + 1e-5f);
  }
}

// ---------------- K5: BN apply + SiLU ----------------
__global__ __launch_bounds__(256) void bn_silu_kernel(
    const float* __restrict__ y, const float* __restrict__ mean,
    const float* __restrict__ invstd, const float* __restrict__ gamma,
    const float* __restrict__ beta, float* __restrict__ out) {
  int i4 = blockIdx.x * blockDim.x + threadIdx.x;   // 2097152 float4s
  int c = (i4 >> 10) & 255;
  float4 v = ((const float4*)y)[i4];
  float m = mean[c], sc = invstd[c] * gamma[c], bt = beta[c];
  float t0 = (v.x - m) * sc + bt;
  float t1 = (v.y - m) * sc + bt;
  float t2 = (v.z - m) * sc + bt;
  float t3 = (v.w - m) * sc + bt;
  float4 o;
  o.x = t0 / (1.f + expf(-t0));
  o.y = t1 / (1.f + expf(-t1));
  o.z = t2 / (1.f + expf(-t2));
  o.w = t3 / (1.f + expf(-t3));
  ((float4*)out)[i4] = o;
}

extern "C" void kernel_launch(void* const* d_in, const int* in_sizes, int n_in,
                              void* d_out, int out_size, void* d_ws, size_t ws_size,
                              hipStream_t stream) {
  const float* x     = (const float*)d_in[0];
  const float* ow    = (const float*)d_in[1];
  const float* ob    = (const float*)d_in[2];
  const float* dw    = (const float*)d_in[3];
  const float* db    = (const float*)d_in[4];
  const float* gamma = (const float*)d_in[5];
  const float* beta  = (const float*)d_in[6];
  float* out = (float*)d_out;

  float* ws     = (float*)d_ws;
  float* off    = ws;                 // 589824
  float* Wt     = ws + 589824;        // 294912
  float* y      = ws + 884736;        // 8388608
  float* mean   = ws + 9273344;       // 256
  float* invstd = ws + 9273600;       // 256

  offset_conv_kernel<<<1152, 256, 0, stream>>>(x, ow, ob, off);
  wt_transpose_kernel<<<1152, 256, 0, stream>>>(dw, Wt);
  deform_gemm_kernel<<<2048, 256, 0, stream>>>(x, off, Wt, db, y);
  bn_stats_kernel<<<256, 256, 0, stream>>>(y, mean, invstd);
  bn_silu_kernel<<<8192, 256, 0, stream>>>(y, mean, invstd, gamma, beta, out);
}

// Round 2
// 286.698 us; speedup vs baseline: 2.4474x; 2.4474x over previous
//
#include <hip/hip_runtime.h>
#include <hip/hip_bf16.h>
#include <math.h>

// (B,Cin,H,W)=(8,128,64,64), Cout=256, K=3, stride=1, pad=1, dil=1
#define B_    8
#define CIN   128
#define Hx    64
#define Wx    64
#define COUT  256
#define HW    4096
#define KTOT  1152      // CIN*9
#define NOFF  18
#define OFFSEG (B_ * NOFF * HW)   // 589824 floats per cin-segment partial

typedef short bf16x8 __attribute__((ext_vector_type(8)));
typedef float f32x4  __attribute__((ext_vector_type(4)));

static __device__ __forceinline__ short f2bf(float f) {
  __hip_bfloat16 h = __float2bfloat16(f);
  return *reinterpret_cast<short*>(&h);
}

// ---------------- K1: offset conv, 18 channels/thread, cin split 4-way ----------------
// blockIdx = seg*128 + r ; thread -> (b,ho,wo). Writes partial sums offp[seg].
__global__ __launch_bounds__(256) void offset_conv_kernel(
    const float* __restrict__ x, const float* __restrict__ ow,
    const float* __restrict__ ob, float* __restrict__ offp) {
  int r = blockIdx.x & 127, seg = blockIdx.x >> 7;
  int v = r * 256 + threadIdx.x;            // 0..32767
  int wo = v & 63, ho = (v >> 6) & 63, b = v >> 12;
  int cin0 = seg * 32;
  float acc[18];
#pragma unroll
  for (int c = 0; c < 18; ++c) acc[c] = 0.f;
  const float* xb = x + (b * CIN + cin0) * HW;
  const float* wb = ow + cin0 * 9;          // ow[c*1152 + cin*9 + tap]
  for (int ci = 0; ci < 32; ++ci) {
    const float* xp = xb + ci * HW;
    float win[9];
#pragma unroll
    for (int ky = 0; ky < 3; ++ky) {
      int iy = ho - 1 + ky;
      bool rok = (iy >= 0) & (iy < Hx);
      const float* rowp = xp + iy * Wx;
#pragma unroll
      for (int kx = 0; kx < 3; ++kx) {
        int ix = wo - 1 + kx;
        win[ky * 3 + kx] = (rok & (ix >= 0) & (ix < Wx)) ? rowp[ix] : 0.f;
      }
    }
    const float* wp = wb + ci * 9;          // uniform address -> scalar loads
#pragma unroll
    for (int c = 0; c < 18; ++c) {
#pragma unroll
      for (int t = 0; t < 9; ++t)
        acc[c] = fmaf(win[t], wp[c * KTOT + t], acc[c]);
    }
  }
  float* op = offp + seg * OFFSEG + (b * NOFF) * HW + ho * 64 + wo;
#pragma unroll
  for (int c = 0; c < 18; ++c)
    op[c * HW] = acc[c] + ((seg == 0) ? ob[c] : 0.f);
}

// ---------------- K2: weight transpose + bf16 convert ----------------
// Wtb[cout*1152 + kk*128 + cin] = bf16(w[cout][cin][kk])
__global__ __launch_bounds__(256) void wt_cvt_kernel(
    const float* __restrict__ w, short* __restrict__ Wtb) {
  int t = blockIdx.x * 256 + threadIdx.x;   // 294912
  int cout = t / KTOT;
  int k = t - cout * KTOT;
  int kk = k >> 7, cin = k & 127;
  Wtb[t] = f2bf(w[(cout * CIN + cin) * 9 + kk]);
}

// ---------------- K3: fused bilinear-sample + bf16 MFMA GEMM ----------------
// C-tile 256(cout) x 128(pos) per block; 512 threads = 8 waves of 64x64.
// K = 1152 in 36 chunks of 32 (one tap kk, 32 cins).
__global__ __launch_bounds__(512, 2) void deform_gemm_kernel(
    const float* __restrict__ x, const float* __restrict__ offp,
    const short* __restrict__ Wtb, const float* __restrict__ db,
    float* __restrict__ y) {
  __shared__ __align__(16) short sa[256 * 40];   // [cout][k] pad 40
  __shared__ __align__(16) short sb[128 * 40];   // [pos][k]  pad 40
  __shared__ short4 sidx[9 * 128];
  __shared__ float4 swt[9 * 128];

  int tid = threadIdx.x;
  int pt = blockIdx.x;                 // 0..255
  int b = pt >> 5;
  int ho0 = (pt & 31) * 2;

  // phase 0: bilinear coeffs per (tap, local pos)
  for (int i = tid; i < 9 * 128; i += 512) {
    int kk = i >> 7, n = i & 127;
    int ho = ho0 + (n >> 6), wo = n & 63;
    int base = (b * NOFF + 2 * kk) * HW + ho * 64 + wo;
    float dy = offp[base] + offp[base + OFFSEG] + offp[base + 2 * OFFSEG] + offp[base + 3 * OFFSEG];
    int base2 = base + HW;
    float dx = offp[base2] + offp[base2 + OFFSEG] + offp[base2 + 2 * OFFSEG] + offp[base2 + 3 * OFFSEG];
    float sy = (float)(ho - 1 + kk / 3) + dy;
    float sx = (float)(wo - 1 + kk % 3) + dx;
    float fy = floorf(sy), fx = floorf(sx);
    int y0 = (int)fy, x0 = (int)fx;
    float wy = sy - fy, wx = sx - fx;
    int y1 = y0 + 1, x1 = x0 + 1;
    int cy0 = min(max(y0, 0), Hx - 1), cy1 = min(max(y1, 0), Hx - 1);
    int cx0 = min(max(x0, 0), Wx - 1), cx1 = min(max(x1, 0), Wx - 1);
    bool vy0 = (y0 >= 0) & (y0 < Hx), vy1 = (y1 >= 0) & (y1 < Hx);
    bool vx0 = (x0 >= 0) & (x0 < Wx), vx1 = (x1 >= 0) & (x1 < Wx);
    short4 id;
    id.x = (short)(cy0 * Wx + cx0); id.y = (short)(cy0 * Wx + cx1);
    id.z = (short)(cy1 * Wx + cx0); id.w = (short)(cy1 * Wx + cx1);
    float4 wv;
    wv.x = (vy0 && vx0) ? (1.f - wy) * (1.f - wx) : 0.f;
    wv.y = (vy0 && vx1) ? (1.f - wy) * wx : 0.f;
    wv.z = (vy1 && vx0) ? wy * (1.f - wx) : 0.f;
    wv.w = (vy1 && vx1) ? wy * wx : 0.f;
    sidx[i] = id; swt[i] = wv;
  }
  __syncthreads();

  int lane = tid & 63, wave = tid >> 6;
  int quad = lane >> 4, l16 = lane & 15;
  int wm = (wave & 3) << 6, wn = (wave >> 2) << 6;

  int acout = tid >> 1, akh = (tid & 1) << 4;     // A-staging role
  int bn = tid & 127, brb = (tid >> 7) << 3;      // B-staging role: 8 cins at pos bn
  const float* xb = x + b * CIN * HW;

  f32x4 zero = {0.f, 0.f, 0.f, 0.f};
  f32x4 acc[4][4];
#pragma unroll
  for (int i = 0; i < 4; ++i)
#pragma unroll
    for (int j = 0; j < 4; ++j) acc[i][j] = zero;

  for (int ch = 0; ch < 36; ++ch) {
    int kk = ch >> 2, cin0 = (ch & 3) << 5;
    // global loads first (overlap with previous chunk's MFMA via other waves)
    const int4* wsrc = (const int4*)&Wtb[acout * KTOT + kk * 128 + cin0 + akh];
    int4 aw0 = wsrc[0];
    int4 aw1 = wsrc[1];   // not used; akh covers 16 bf16 = 2 int4? -> see below
    short4 id = sidx[kk * 128 + bn];
    float4 wv = swt[kk * 128 + bn];
    union { short s[8]; int4 v; } bu;
    const float* xp = xb + (cin0 + brb) * HW;
#pragma unroll
    for (int c = 0; c < 8; ++c) {
      const float* p = xp + c * HW;
      float vsm = wv.x * p[(int)id.x] + wv.y * p[(int)id.y]
                + wv.z * p[(int)id.z] + wv.w * p[(int)id.w];
      bu.s[c] = f2bf(vsm);
    }
    __syncthreads();   // previous chunk's frag reads done
    *(int4*)&sa[acout * 40 + akh] = aw0;
    *(int4*)&sa[acout * 40 + akh + 8] = aw1;
    *(int4*)&sb[bn * 40 + brb] = bu.v;
    __syncthreads();

    bf16x8 af[4], bfr[4];
#pragma unroll
    for (int i = 0; i < 4; ++i)
      af[i] = *(const bf16x8*)&sa[(wm + i * 16 + l16) * 40 + quad * 8];
#pragma unroll
    for (int j = 0; j < 4; ++j)
      bfr[j] = *(const bf16x8*)&sb[(wn + j * 16 + l16) * 40 + quad * 8];
#pragma unroll
    for (int i = 0; i < 4; ++i)
#pragma unroll
      for (int j = 0; j < 4; ++j)
        acc[i][j] = __builtin_amdgcn_mfma_f32_16x16x32_bf16(af[i], bfr[j], acc[i][j], 0, 0, 0);
  }

  // epilogue: + bias, store y[(b,cout,ho,wo)]
#pragma unroll
  for (int i = 0; i < 4; ++i) {
    int m0 = wm + i * 16 + quad * 4;
#pragma unroll
    for (int j = 0; j < 4; ++j) {
      int n = wn + j * 16 + l16;
      int ho = ho0 + (n >> 6), wo = n & 63;
      float* yp = y + (b * COUT + m0) * HW + ho * 64 + wo;
#pragma unroll
      for (int r2 = 0; r2 < 4; ++r2)
        yp[r2 * HW] = acc[i][j][r2] + db[m0 + r2];
    }
  }
}

// ---------------- K4: BN batch stats ----------------
__global__ __launch_bounds__(256) void bn_stats_kernel(
    const float* __restrict__ y, float* __restrict__ mean, float* __restrict__ invstd) {
  int c = blockIdx.x;
  int tid = threadIdx.x;
  float s = 0.f, s2 = 0.f;
  for (int b = 0; b < B_; ++b) {
    const float* p = y + (b * COUT + c) * HW;
    for (int i = tid; i < HW; i += 256) {
      float v = p[i];
      s += v; s2 = fmaf(v, v, s2);
    }
  }
#pragma unroll
  for (int o = 32; o > 0; o >>= 1) {
    s  += __shfl_down(s, o);
    s2 += __shfl_down(s2, o);
  }
  __shared__ float rs[4], rs2[4];
  int wid = tid >> 6, ln = tid & 63;
  if (ln == 0) { rs[wid] = s; rs2[wid] = s2; }
  __syncthreads();
  if (tid == 0) {
    float S  = rs[0] + rs[1] + rs[2] + rs[3];
    float S2 = rs2[0] + rs2[1] + rs2[2] + rs2[3];
    float m = S / 32768.f;
    float var = S2 / 32768.f - m * m;
    mean[c] = m;
    invstd[c] = rsqrtf(var + 1e-5f);
  }
}

// ---------------- K5: BN apply + SiLU ----------------
__global__ __launch_bounds__(256) void bn_silu_kernel(
    const float* __restrict__ y, const float* __restrict__ mean,
    const float* __restrict__ invstd, const float* __restrict__ gamma,
    const float* __restrict__ beta, float* __restrict__ out) {
  int i4 = blockIdx.x * blockDim.x + threadIdx.x;   // 2097152 float4s
  int c = (i4 >> 10) & 255;
  float4 v = ((const float4*)y)[i4];
  float m = mean[c], sc = invstd[c] * gamma[c], bt = beta[c];
  float t0 = (v.x - m) * sc + bt;
  float t1 = (v.y - m) * sc + bt;
  float t2 = (v.z - m) * sc + bt;
  float t3 = (v.w - m) * sc + bt;
  float4 o;
  o.x = t0 / (1.f + expf(-t0));
  o.y = t1 / (1.f + expf(-t1));
  o.z = t2 / (1.f + expf(-t2));
  o.w = t3 / (1.f + expf(-t3));
  ((float4*)out)[i4] = o;
}

extern "C" void kernel_launch(void* const* d_in, const int* in_sizes, int n_in,
                              void* d_out, int out_size, void* d_ws, size_t ws_size,
                              hipStream_t stream) {
  const float* x     = (const float*)d_in[0];
  const float* ow    = (const float*)d_in[1];
  const float* ob    = (const float*)d_in[2];
  const float* dw    = (const float*)d_in[3];
  const float* db    = (const float*)d_in[4];
  const float* gamma = (const float*)d_in[5];
  const float* beta  = (const float*)d_in[6];
  float* out = (float*)d_out;

  float* ws     = (float*)d_ws;
  float* offp   = ws;                        // 4 * 589824
  short* Wtb    = (short*)(ws + 2359296);    // 294912 bf16
  float* y      = ws + 2506752;              // 8388608
  float* mean   = ws + 10895360;             // 256
  float* invstd = ws + 10895616;             // 256

  offset_conv_kernel<<<512, 256, 0, stream>>>(x, ow, ob, offp);
  wt_cvt_kernel<<<1152, 256, 0, stream>>>(dw, Wtb);
  deform_gemm_kernel<<<256, 512, 0, stream>>>(x, offp, Wtb, db, y);
  bn_stats_kernel<<<256, 256, 0, stream>>>(y, mean, invstd);
  bn_silu_kernel<<<8192, 256, 0, stream>>>(y, mean, invstd, gamma, beta, out);
}

// Round 5
// 281.822 us; speedup vs baseline: 2.4898x; 1.0173x over previous
//
#include <hip/hip_runtime.h>
#include <hip/hip_bf16.h>
#include <math.h>

// (B,Cin,H,W)=(8,128,64,64), Cout=256, K=3, stride=1, pad=1, dil=1
#define B_    8
#define CIN   128
#define Hx    64
#define Wx    64
#define COUT  256
#define HW    4096
#define KTOT  1152      // CIN*9
#define NOFF  18
#define OFFSEG (B_ * NOFF * HW)   // 589824 floats per cin-segment partial
#define YPART 8388608             // B_*COUT*HW floats per K-half partial

typedef short bf16x8 __attribute__((ext_vector_type(8)));
typedef float f32x4  __attribute__((ext_vector_type(4)));

static __device__ __forceinline__ short f2bf(float f) {
  __hip_bfloat16 h = __float2bfloat16(f);
  return *reinterpret_cast<short*>(&h);
}

// ---------------- K1: offset conv, 18 channels/thread, cin split 4-way ----------------
// (verbatim from passed round 2)
__global__ __launch_bounds__(256) void offset_conv_kernel(
    const float* __restrict__ x, const float* __restrict__ ow,
    const float* __restrict__ ob, float* __restrict__ offp) {
  int r = blockIdx.x & 127, seg = blockIdx.x >> 7;
  int v = r * 256 + threadIdx.x;            // 0..32767
  int wo = v & 63, ho = (v >> 6) & 63, b = v >> 12;
  int cin0 = seg * 32;
  float acc[18];
#pragma unroll
  for (int c = 0; c < 18; ++c) acc[c] = 0.f;
  const float* xb = x + (b * CIN + cin0) * HW;
  const float* wb = ow + cin0 * 9;          // ow[c*1152 + cin*9 + tap]
  for (int ci = 0; ci < 32; ++ci) {
    const float* xp = xb + ci * HW;
    float win[9];
#pragma unroll
    for (int ky = 0; ky < 3; ++ky) {
      int iy = ho - 1 + ky;
      bool rok = (iy >= 0) & (iy < Hx);
      const float* rowp = xp + iy * Wx;
#pragma unroll
      for (int kx = 0; kx < 3; ++kx) {
        int ix = wo - 1 + kx;
        win[ky * 3 + kx] = (rok & (ix >= 0) & (ix < Wx)) ? rowp[ix] : 0.f;
      }
    }
    const float* wp = wb + ci * 9;          // wave-uniform -> scalar loads
#pragma unroll
    for (int c = 0; c < 18; ++c) {
#pragma unroll
      for (int t = 0; t < 9; ++t)
        acc[c] = fmaf(win[t], wp[c * KTOT + t], acc[c]);
    }
  }
  float* op = offp + seg * OFFSEG + (b * NOFF) * HW + ho * 64 + wo;
#pragma unroll
  for (int c = 0; c < 18; ++c)
    op[c * HW] = acc[c] + ((seg == 0) ? ob[c] : 0.f);
}

// ---------------- K2: weight transpose + bf16 convert (verbatim round 2) ----------------
__global__ __launch_bounds__(256) void wt_cvt_kernel(
    const float* __restrict__ w, short* __restrict__ Wtb) {
  int t = blockIdx.x * 256 + threadIdx.x;   // 294912
  int cout = t / KTOT;
  int k = t - cout * KTOT;
  int kk = k >> 7, cin = k & 127;
  Wtb[t] = f2bf(w[(cout * CIN + cin) * 9 + kk]);
}

// ---------------- K3: fused bilinear-sample + bf16 MFMA GEMM (round-2 body, K-split) ----------------
// C-tile 256(cout) x 128(pos); 512 threads = 8 waves of 64x64.
// K-SPLIT: blockIdx = pt*2 + khalf; each half does 18 of 36 chunks and writes
// ypart[khalf]. GEMM inner structure is BIT-IDENTICAL to the passed round 2.
__global__ __launch_bounds__(512, 2) void deform_gemm_kernel(
    const float* __restrict__ x, const float* __restrict__ offp,
    const short* __restrict__ Wtb, float* __restrict__ ypart) {
  __shared__ __align__(16) short sa[256 * 40];   // [cout][k] pad 40
  __shared__ __align__(16) short sb[128 * 40];   // [pos][k]  pad 40
  __shared__ short4 sidx[9 * 128];
  __shared__ float4 swt[9 * 128];

  int tid = threadIdx.x;
  int bb = blockIdx.x;                 // 0..511
  int khalf = bb & 1;
  int pt = bb >> 1;                    // 0..255
  int b = pt >> 5;
  int ho0 = (pt & 31) * 2;

  // phase 0: bilinear coeffs per (tap, local pos)
  for (int i = tid; i < 9 * 128; i += 512) {
    int kk = i >> 7, n = i & 127;
    int ho = ho0 + (n >> 6), wo = n & 63;
    int base = (b * NOFF + 2 * kk) * HW + ho * 64 + wo;
    float dy = offp[base] + offp[base + OFFSEG] + offp[base + 2 * OFFSEG] + offp[base + 3 * OFFSEG];
    int base2 = base + HW;
    float dx = offp[base2] + offp[base2 + OFFSEG] + offp[base2 + 2 * OFFSEG] + offp[base2 + 3 * OFFSEG];
    float sy = (float)(ho - 1 + kk / 3) + dy;
    float sx = (float)(wo - 1 + kk % 3) + dx;
    float fy = floorf(sy), fx = floorf(sx);
    int y0 = (int)fy, x0 = (int)fx;
    float wy = sy - fy, wx = sx - fx;
    int y1 = y0 + 1, x1 = x0 + 1;
    int cy0 = min(max(y0, 0), Hx - 1), cy1 = min(max(y1, 0), Hx - 1);
    int cx0 = min(max(x0, 0), Wx - 1), cx1 = min(max(x1, 0), Wx - 1);
    bool vy0 = (y0 >= 0) & (y0 < Hx), vy1 = (y1 >= 0) & (y1 < Hx);
    bool vx0 = (x0 >= 0) & (x0 < Wx), vx1 = (x1 >= 0) & (x1 < Wx);
    short4 id;
    id.x = (short)(cy0 * Wx + cx0); id.y = (short)(cy0 * Wx + cx1);
    id.z = (short)(cy1 * Wx + cx0); id.w = (short)(cy1 * Wx + cx1);
    float4 wv;
    wv.x = (vy0 && vx0) ? (1.f - wy) * (1.f - wx) : 0.f;
    wv.y = (vy0 && vx1) ? (1.f - wy) * wx : 0.f;
    wv.z = (vy1 && vx0) ? wy * (1.f - wx) : 0.f;
    wv.w = (vy1 && vx1) ? wy * wx : 0.f;
    sidx[i] = id; swt[i] = wv;
  }
  __syncthreads();

  int lane = tid & 63, wave = tid >> 6;
  int quad = lane >> 4, l16 = lane & 15;
  int wm = (wave & 3) << 6, wn = (wave >> 2) << 6;

  int acout = tid >> 1, akh = (tid & 1) << 4;     // A-staging role
  int bn = tid & 127, brb = (tid >> 7) << 3;      // B-staging role: 8 cins at pos bn
  const float* xb = x + b * CIN * HW;

  f32x4 zero = {0.f, 0.f, 0.f, 0.f};
  f32x4 acc[4][4];
#pragma unroll
  for (int i = 0; i < 4; ++i)
#pragma unroll
    for (int j = 0; j < 4; ++j) acc[i][j] = zero;

  for (int ch = khalf * 18; ch < khalf * 18 + 18; ++ch) {
    int kk = ch >> 2, cin0 = (ch & 3) << 5;
    // global loads first (overlap with previous chunk's MFMA via other waves)
    const int4* wsrc = (const int4*)&Wtb[acout * KTOT + kk * 128 + cin0 + akh];
    int4 aw0 = wsrc[0];
    int4 aw1 = wsrc[1];
    short4 id = sidx[kk * 128 + bn];
    float4 wv = swt[kk * 128 + bn];
    union { short s[8]; int4 v; } bu;
    const float* xp = xb + (cin0 + brb) * HW;
#pragma unroll
    for (int c = 0; c < 8; ++c) {
      const float* p = xp + c * HW;
      float vsm = wv.x * p[(int)id.x] + wv.y * p[(int)id.y]
                + wv.z * p[(int)id.z] + wv.w * p[(int)id.w];
      bu.s[c] = f2bf(vsm);
    }
    __syncthreads();   // previous chunk's frag reads done
    *(int4*)&sa[acout * 40 + akh] = aw0;
    *(int4*)&sa[acout * 40 + akh + 8] = aw1;
    *(int4*)&sb[bn * 40 + brb] = bu.v;
    __syncthreads();

    bf16x8 af[4], bfr[4];
#pragma unroll
    for (int i = 0; i < 4; ++i)
      af[i] = *(const bf16x8*)&sa[(wm + i * 16 + l16) * 40 + quad * 8];
#pragma unroll
    for (int j = 0; j < 4; ++j)
      bfr[j] = *(const bf16x8*)&sb[(wn + j * 16 + l16) * 40 + quad * 8];
#pragma unroll
    for (int i = 0; i < 4; ++i)
#pragma unroll
      for (int j = 0; j < 4; ++j)
        acc[i][j] = __builtin_amdgcn_mfma_f32_16x16x32_bf16(af[i], bfr[j], acc[i][j], 0, 0, 0);
  }

  // epilogue: store K-half partial (no bias — it cancels in BN mean-subtraction)
  float* yh = ypart + khalf * YPART;
#pragma unroll
  for (int i = 0; i < 4; ++i) {
    int m0 = wm + i * 16 + quad * 4;
#pragma unroll
    for (int j = 0; j < 4; ++j) {
      int n = wn + j * 16 + l16;
      int ho = ho0 + (n >> 6), wo = n & 63;
      float* yp = yh + (b * COUT + m0) * HW + ho * 64 + wo;
#pragma unroll
      for (int r2 = 0; r2 < 4; ++r2)
        yp[r2 * HW] = acc[i][j][r2];
    }
  }
}

// ---------------- K4: BN batch stats over (y0 + y1) ----------------
__global__ __launch_bounds__(256) void bn_stats_kernel(
    const float* __restrict__ y, float* __restrict__ mean, float* __restrict__ invstd) {
  int c = blockIdx.x;
  int tid = threadIdx.x;
  float s = 0.f, s2 = 0.f;
  for (int b = 0; b < B_; ++b) {
    const float4* p0 = (const float4*)(y + (b * COUT + c) * HW);
    const float4* p1 = (const float4*)(y + YPART + (b * COUT + c) * HW);
    for (int i = tid; i < HW / 4; i += 256) {
      float4 a = p0[i], bv = p1[i];
      float v0 = a.x + bv.x, v1 = a.y + bv.y, v2 = a.z + bv.z, v3 = a.w + bv.w;
      s += v0 + v1 + v2 + v3;
      s2 = fmaf(v0, v0, s2); s2 = fmaf(v1, v1, s2);
      s2 = fmaf(v2, v2, s2); s2 = fmaf(v3, v3, s2);
    }
  }
#pragma unroll
  for (int o = 32; o > 0; o >>= 1) {
    s  += __shfl_down(s, o);
    s2 += __shfl_down(s2, o);
  }
  __shared__ float rs[4], rs2[4];
  int wid = tid >> 6, ln = tid & 63;
  if (ln == 0) { rs[wid] = s; rs2[wid] = s2; }
  __syncthreads();
  if (tid == 0) {
    float S  = rs[0] + rs[1] + rs[2] + rs[3];
    float S2 = rs2[0] + rs2[1] + rs2[2] + rs2[3];
    float m = S / 32768.f;
    float var = S2 / 32768.f - m * m;
    mean[c] = m;
    invstd[c] = rsqrtf(var + 1e-5f);
  }
}

// ---------------- K5: BN apply + SiLU over (y0 + y1) ----------------
__global__ __launch_bounds__(256) void bn_silu_kernel(
    const float* __restrict__ y, const float* __restrict__ mean,
    const float* __restrict__ invstd, const float* __restrict__ gamma,
    const float* __restrict__ beta, float* __restrict__ out) {
  int i4 = blockIdx.x * 256 + threadIdx.x;   // 2097152 float4s
  int c = (i4 >> 10) & 255;
  float4 a = ((const float4*)y)[i4];
  float4 bv = ((const float4*)(y + YPART))[i4];
  float m = mean[c], sc = invstd[c] * gamma[c], bt = beta[c];
  float t0 = (a.x + bv.x - m) * sc + bt;
  float t1 = (a.y + bv.y - m) * sc + bt;
  float t2 = (a.z + bv.z - m) * sc + bt;
  float t3 = (a.w + bv.w - m) * sc + bt;
  float4 o;
  o.x = t0 / (1.f + expf(-t0));
  o.y = t1 / (1.f + expf(-t1));
  o.z = t2 / (1.f + expf(-t2));
  o.w = t3 / (1.f + expf(-t3));
  ((float4*)out)[i4] = o;
}

extern "C" void kernel_launch(void* const* d_in, const int* in_sizes, int n_in,
                              void* d_out, int out_size, void* d_ws, size_t ws_size,
                              hipStream_t stream) {
  const float* x     = (const float*)d_in[0];
  const float* ow    = (const float*)d_in[1];
  const float* ob    = (const float*)d_in[2];
  const float* dw    = (const float*)d_in[3];
  // d_in[4] = dconv bias: exactly cancelled by BN mean-subtraction (and zero in setup)
  const float* gamma = (const float*)d_in[5];
  const float* beta  = (const float*)d_in[6];
  float* out = (float*)d_out;

  float* ws     = (float*)d_ws;
  float* offp   = ws;                        // 4 * 589824 = 2359296
  short* Wtb    = (short*)(ws + 2359296);    // 294912 bf16 (147456 floats)
  float* y      = ws + 2506752;              // 2 * 8388608 (K-half partials)
  float* mean   = ws + 19283968;             // 256
  float* invstd = ws + 19284224;             // 256

  offset_conv_kernel<<<512, 256, 0, stream>>>(x, ow, ob, offp);
  wt_cvt_kernel<<<1152, 256, 0, stream>>>(dw, Wtb);
  deform_gemm_kernel<<<512, 512, 0, stream>>>(x, offp, Wtb, y);
  bn_stats_kernel<<<256, 256, 0, stream>>>(y, mean, invstd);
  bn_silu_kernel<<<8192, 256, 0, stream>>>(y, mean, invstd, gamma, beta, out);
}